// Round 1
// baseline (2557.736 us; speedup 1.0000x reference)
//
#include <hip/hip_runtime.h>

#define LRC   0.05f
#define B1C   0.9f
#define B2C   0.999f
#define C1C   0.1f      // float(1 - 0.9)
#define C2C   0.001f    // float(1 - 0.999)
#define EPSC  1e-8f

__device__ __forceinline__ float rlane(float v, int l) {
  return __int_as_float(__builtin_amdgcn_readlane(__float_as_int(v), l));
}

__device__ __forceinline__ float wsum(float v) {
  #pragma unroll
  for (int off = 1; off < 64; off <<= 1) v += __shfl_xor(v, off, 64);
  return v;
}

// ---------------- K1: encode all tokens t=0..30 per sample ----------------
// block = 256 (4 waves), one sample per block; wave w handles tokens [8w, 8w+8)
// (wave 3 pads its 8th token with a duplicate of t=30, store-masked).
__global__ __launch_bounds__(256, 4) void encode_kernel(
    const int* __restrict__ seqs, const float* __restrict__ embed,
    const float* __restrict__ ff_w1, const float* __restrict__ ff_b1,
    const float* __restrict__ ff_w2, const float* __restrict__ ff_b2,
    const float* __restrict__ ln_g, const float* __restrict__ ln_b,
    float* __restrict__ hws)
{
  const int sample = blockIdx.x;
  const int wave = threadIdx.x >> 6;
  const int lane = threadIdx.x & 63;
  const int t0 = wave * 8;

  // tokens as wave-uniform scalars
  int tokv = seqs[sample * 32 + (lane & 31)];
  int toks[8];
  #pragma unroll
  for (int tt = 0; tt < 8; ++tt)
    toks[tt] = __builtin_amdgcn_readlane(tokv, t0 + tt); // t0+7 = 31 for wave 3: padded, masked at store

  float e[8];
  #pragma unroll
  for (int tt = 0; tt < 8; ++tt) e[tt] = embed[toks[tt] * 64 + lane];

  // ---- layer 1: hid[i] for i = lane, lane+64, 8 tokens register-blocked ----
  float acc0[8], acc1[8];
  {
    float b1a = ff_b1[lane], b1b = ff_b1[lane + 64];
    #pragma unroll
    for (int tt = 0; tt < 8; ++tt) { acc0[tt] = b1a; acc1[tt] = b1b; }
  }
  #pragma unroll
  for (int j4 = 0; j4 < 16; ++j4) {
    float es[8][4];
    #pragma unroll
    for (int tt = 0; tt < 8; ++tt) {
      float4 v4 = *(const float4*)(embed + toks[tt] * 64 + j4 * 4); // uniform -> s_load_dwordx4
      es[tt][0] = v4.x; es[tt][1] = v4.y; es[tt][2] = v4.z; es[tt][3] = v4.w;
    }
    #pragma unroll
    for (int u = 0; u < 4; ++u) {
      const int jj = j4 * 4 + u;
      float wa = ff_w1[jj * 128 + lane];
      float wb = ff_w1[jj * 128 + lane + 64];
      #pragma unroll
      for (int tt = 0; tt < 8; ++tt) {
        acc0[tt] = fmaf(es[tt][u], wa, acc0[tt]);
        acc1[tt] = fmaf(es[tt][u], wb, acc1[tt]);
      }
    }
  }
  #pragma unroll
  for (int tt = 0; tt < 8; ++tt) {
    acc0[tt] = fmaxf(acc0[tt], 0.f);
    acc1[tt] = fmaxf(acc1[tt], 0.f);
  }

  // ---- layer 2: f[j] = b2[j] + sum_i hid[i]*w2[i][j], hid broadcast via readlane ----
  float f[8];
  {
    float b2v = ff_b2[lane];
    #pragma unroll
    for (int tt = 0; tt < 8; ++tt) f[tt] = b2v;
  }
  #pragma unroll
  for (int l = 0; l < 64; ++l) {
    float wlo = ff_w2[l * 64 + lane];
    float whi = ff_w2[(l + 64) * 64 + lane];
    #pragma unroll
    for (int tt = 0; tt < 8; ++tt) {
      f[tt] = fmaf(rlane(acc0[tt], l), wlo, f[tt]);
      f[tt] = fmaf(rlane(acc1[tt], l), whi, f[tt]);
    }
  }

  // ---- residual + LN + store ----
  float gg = ln_g[lane], bb = ln_b[lane];
  #pragma unroll
  for (int tt = 0; tt < 8; ++tt) {
    float x = e[tt] + f[tt];
    float mu = wsum(x) * (1.f / 64.f);
    float d = x - mu;
    float var = wsum(d * d) * (1.f / 64.f);
    float h = d * (1.f / sqrtf(var + 1e-5f)) * gg + bb;
    int t = t0 + tt;
    if (t < 31)
      hws[(size_t)sample * 1984 + t * 64 + lane] = h;
  }
}

// ---------------- Adam per-param update ----------------
__device__ __forceinline__ void adam1(float& p, float& m, float& v, float g,
                                      float rc1, float rc2) {
  m = fmaf(B1C, m, C1C * g);
  v = fmaf(B2C, v, (C2C * g) * g);
  float den = sqrtf(v * rc2) + EPSC;
  p = fmaf(-LRC, __fdividef(m * rc1, den), p);
}

// ---------------- K2: scores -> evict-min buffer -> 8 Adam steps -> query ----------------
// block = 256 (4 waves), one sample per wave; lane = feature index j.
__global__ __launch_bounds__(256, 2) void adam_kernel(
    const float* __restrict__ hws,
    const float* __restrict__ scorer_w, const float* __restrict__ scorer_b,
    const float* __restrict__ mlp_w1, const float* __restrict__ mlp_b1,
    const float* __restrict__ mlp_w2, const float* __restrict__ mlp_b2,
    const float* __restrict__ out_w, const float* __restrict__ out_b,
    float* __restrict__ out)
{
  const int wave = threadIdx.x >> 6;
  const int lane = threadIdx.x & 63;
  const int sample = blockIdx.x * 4 + wave;
  const float* hb = hws + (size_t)sample * 1984;

  // ---- scores (replicated across lanes via butterfly) ----
  float swk = scorer_w[lane], swv = scorer_w[64 + lane];
  float sb = scorer_b[0];
  float kk[15], vv[15], sc[15];
  #pragma unroll
  for (int p = 0; p < 15; ++p) {
    kk[p] = hb[(2 * p) * 64 + lane];
    vv[p] = hb[(2 * p + 1) * 64 + lane];
    sc[p] = wsum(kk[p] * swk + vv[p] * swv) + sb;
  }

  // ---- buffer: first 8, then 7 evict-min(first occurrence)+append ----
  float bk[8], bv[8], bs[8];
  #pragma unroll
  for (int i = 0; i < 8; ++i) { bk[i] = kk[i]; bv[i] = vv[i]; bs[i] = sc[i]; }
  #pragma unroll
  for (int n = 0; n < 7; ++n) {
    int mi = 0; float ms = bs[0];
    #pragma unroll
    for (int i = 1; i < 8; ++i) {
      bool lt = bs[i] < ms;            // strict < keeps FIRST min, matching argmin
      if (lt) { mi = i; ms = bs[i]; }
    }
    #pragma unroll
    for (int i = 0; i < 7; ++i) {
      bool sh = i >= mi;               // pop(mi): shift left
      bs[i] = sh ? bs[i + 1] : bs[i];
      bk[i] = sh ? bk[i + 1] : bk[i];
      bv[i] = sh ? bv[i + 1] : bv[i];
    }
    bs[7] = sc[8 + n]; bk[7] = kk[8 + n]; bv[7] = vv[8 + n];
  }

  // ---- tmp MLP params: lane j holds w1 row j, w2 col j; b1 lane-distributed ----
  float w1r[24], w2c[24], m1[24], v1[24], m2[24], v2[24];
  #pragma unroll
  for (int c = 0; c < 24; ++c) {
    w1r[c] = mlp_w1[lane * 24 + c];
    w2c[c] = mlp_w2[c * 64 + lane];
    m1[c] = v1[c] = m2[c] = v2[c] = 0.f;
  }
  float b1o = 0.f;
  if (lane < 24) b1o = mlp_b1[lane];
  float b2o = mlp_b2[lane];
  float mb1 = 0.f, vb1 = 0.f, mb2 = 0.f, vb2 = 0.f;
  float p1t = 1.f, p2t = 1.f;

  #pragma unroll 1
  for (int step = 0; step < 8; ++step) {
    // select (k,v) pair `step` (static unrolled cndmask chain)
    float kj = bk[0], vj = bv[0];
    #pragma unroll
    for (int i = 1; i < 8; ++i)
      if (step == i) { kj = bk[i]; vj = bv[i]; }

    p1t *= B1C; p2t *= B2C;
    float rc1 = __fdividef(1.f, 1.f - p1t);
    float rc2 = __fdividef(1.f, 1.f - p2t);

    // fwd layer1: pre[c] = b1[c] + sum_j k_j*w1[j][c]  (replicated)
    float pre[24];
    #pragma unroll
    for (int c = 0; c < 24; ++c) pre[c] = kj * w1r[c];
    #pragma unroll
    for (int off = 1; off < 64; off <<= 1) {
      #pragma unroll
      for (int c = 0; c < 24; ++c) pre[c] += __shfl_xor(pre[c], off, 64);
    }
    #pragma unroll
    for (int c = 0; c < 24; ++c) pre[c] += rlane(b1o, c);

    // fwd layer2 (lane-local): out_j = b2_j + sum_c relu(pre[c])*w2[c][j]
    float outv = b2o;
    #pragma unroll
    for (int c = 0; c < 24; ++c) outv = fmaf(fmaxf(pre[c], 0.f), w2c[c], outv);

    float dout = (outv - vj) * (2.f / 64.f);

    // dh[c] = sum_j w2[c][j]*dout_j  (replicated)
    float dh[24];
    #pragma unroll
    for (int c = 0; c < 24; ++c) dh[c] = w2c[c] * dout;
    #pragma unroll
    for (int off = 1; off < 64; off <<= 1) {
      #pragma unroll
      for (int c = 0; c < 24; ++c) dh[c] += __shfl_xor(dh[c], off, 64);
    }

    // dpre = dh * relu'(pre); pick own dpre[lane] for b1 grad
    float dpre_own = 0.f;
    #pragma unroll
    for (int c = 0; c < 24; ++c) {
      float dp = (pre[c] > 0.f) ? dh[c] : 0.f;
      dh[c] = dp;
      if (lane == c) dpre_own = dp;
    }

    // Adam updates
    #pragma unroll
    for (int c = 0; c < 24; ++c) {
      adam1(w1r[c], m1[c], v1[c], kj * dh[c], rc1, rc2);                 // gw1[j][c]
      adam1(w2c[c], m2[c], v2[c], fmaxf(pre[c], 0.f) * dout, rc1, rc2);  // gw2[c][j]
    }
    adam1(b1o, mb1, vb1, dpre_own, rc1, rc2);
    adam1(b2o, mb2, vb2, dout, rc1, rc2);
  }

  // ---- query: h[30] through finetuned MLP, then output head ----
  float qj = hb[30 * 64 + lane];
  float pre[24];
  #pragma unroll
  for (int c = 0; c < 24; ++c) pre[c] = qj * w1r[c];
  #pragma unroll
  for (int off = 1; off < 64; off <<= 1) {
    #pragma unroll
    for (int c = 0; c < 24; ++c) pre[c] += __shfl_xor(pre[c], off, 64);
  }
  #pragma unroll
  for (int c = 0; c < 24; ++c) pre[c] += rlane(b1o, c);
  float y = b2o;
  #pragma unroll
  for (int c = 0; c < 24; ++c) y = fmaf(fmaxf(pre[c], 0.f), w2c[c], y);

  float acc = out_b[lane];
  #pragma unroll
  for (int l = 0; l < 64; ++l)
    acc = fmaf(rlane(y, l), out_w[l * 64 + lane], acc);

  out[(size_t)sample * 64 + lane] = acc;
}

extern "C" void kernel_launch(void* const* d_in, const int* in_sizes, int n_in,
                              void* d_out, int out_size, void* d_ws, size_t ws_size,
                              hipStream_t stream) {
  const int*   seqs     = (const int*)d_in[0];
  const float* embed    = (const float*)d_in[1];
  const float* ff_w1    = (const float*)d_in[2];
  const float* ff_b1    = (const float*)d_in[3];
  const float* ff_w2    = (const float*)d_in[4];
  const float* ff_b2    = (const float*)d_in[5];
  const float* ln_g     = (const float*)d_in[6];
  const float* ln_b     = (const float*)d_in[7];
  const float* scorer_w = (const float*)d_in[8];
  const float* scorer_b = (const float*)d_in[9];
  const float* mlp_w1   = (const float*)d_in[10];
  const float* mlp_b1   = (const float*)d_in[11];
  const float* mlp_w2   = (const float*)d_in[12];
  const float* mlp_b2   = (const float*)d_in[13];
  const float* out_w    = (const float*)d_in[14];
  const float* out_b    = (const float*)d_in[15];

  const int B = in_sizes[0] / 32;      // 16384
  float* hws = (float*)d_ws;           // needs B*31*64*4 = 130 MB

  encode_kernel<<<B, 256, 0, stream>>>(seqs, embed, ff_w1, ff_b1, ff_w2, ff_b2,
                                       ln_g, ln_b, hws);
  adam_kernel<<<B / 4, 256, 0, stream>>>(hws, scorer_w, scorer_b,
                                         mlp_w1, mlp_b1, mlp_w2, mlp_b2,
                                         out_w, out_b, (float*)d_out);
}

// Round 3
// 686.515 us; speedup vs baseline: 3.7257x; 3.7257x over previous
//
#include <hip/hip_runtime.h>

#define LRC   0.05f
#define B1C   0.9f
#define B2C   0.999f
#define C1C   0.1f      // float(1 - 0.9)
#define C2C   0.001f    // float(1 - 0.999)
#define EPSC  1e-8f

__device__ __forceinline__ float rlane(float v, int l) {
  return __int_as_float(__builtin_amdgcn_readlane(__float_as_int(v), l));
}

// sum-reduce step within 16-lane row via DPP rotate (VALU pipe, no LDS traffic)
// CTRL must be a compile-time constant -> template parameter.
template <int CTRL>
__device__ __forceinline__ float dpp_add(float x) {
  int y = __builtin_amdgcn_update_dpp(0, __float_as_int(x), CTRL, 0xF, 0xF, false);
  return x + __int_as_float(y);
}

// full-wave sum, result replicated in all 64 lanes
__device__ __forceinline__ float wave_sum_repl(float x) {
  x = dpp_add<0x121>(x);            // row_ror:1
  x = dpp_add<0x122>(x);            // row_ror:2
  x = dpp_add<0x124>(x);            // row_ror:4
  x = dpp_add<0x128>(x);            // row_ror:8  -> row sums
  x += __shfl_xor(x, 16, 64);
  x += __shfl_xor(x, 32, 64);
  return x;
}

// batch of N replicated wave sums, stage-interleaved for ILP
template <int N>
__device__ __forceinline__ void wave_sum_batch(float* a) {
  #pragma unroll
  for (int c = 0; c < N; ++c) a[c] = dpp_add<0x121>(a[c]);
  #pragma unroll
  for (int c = 0; c < N; ++c) a[c] = dpp_add<0x122>(a[c]);
  #pragma unroll
  for (int c = 0; c < N; ++c) a[c] = dpp_add<0x124>(a[c]);
  #pragma unroll
  for (int c = 0; c < N; ++c) a[c] = dpp_add<0x128>(a[c]);
  #pragma unroll
  for (int c = 0; c < N; ++c) a[c] += __shfl_xor(a[c], 16, 64);
  #pragma unroll
  for (int c = 0; c < N; ++c) a[c] += __shfl_xor(a[c], 32, 64);
}

// ---------------- K1: encode table for the 64 distinct tokens ----------------
// encode() is sample/position independent -> only V=64 distinct encodings.
// Also factor the scorer: score(a,b) = sA[a] + sB[b] + scorer_b.
// One block (1 wave) per token.
__global__ void enc_kernel(
    const float* __restrict__ embed,
    const float* __restrict__ ff_w1, const float* __restrict__ ff_b1,
    const float* __restrict__ ff_w2, const float* __restrict__ ff_b2,
    const float* __restrict__ ln_g, const float* __restrict__ ln_b,
    const float* __restrict__ scorer_w,
    float* __restrict__ enc, float* __restrict__ sAt, float* __restrict__ sBt)
{
  const int b = blockIdx.x;      // token id
  const int lane = threadIdx.x;  // feature

  float e = embed[b * 64 + lane];
  float acc0 = ff_b1[lane], acc1 = ff_b1[64 + lane];
  #pragma unroll
  for (int j = 0; j < 64; ++j) {
    float ej = rlane(e, j);
    acc0 = fmaf(ej, ff_w1[j * 128 + lane], acc0);
    acc1 = fmaf(ej, ff_w1[j * 128 + 64 + lane], acc1);
  }
  acc0 = fmaxf(acc0, 0.f);
  acc1 = fmaxf(acc1, 0.f);

  float f = ff_b2[lane];
  #pragma unroll
  for (int l = 0; l < 64; ++l) {
    f = fmaf(rlane(acc0, l), ff_w2[l * 64 + lane], f);
    f = fmaf(rlane(acc1, l), ff_w2[(l + 64) * 64 + lane], f);
  }

  float x = e + f;
  float mu = wave_sum_repl(x) * (1.f / 64.f);
  float d = x - mu;
  float var = wave_sum_repl(d * d) * (1.f / 64.f);
  float h = d * (1.f / sqrtf(var + 1e-5f)) * ln_g[lane] + ln_b[lane];
  enc[b * 64 + lane] = h;

  float sa = wave_sum_repl(h * scorer_w[lane]);
  float sb = wave_sum_repl(h * scorer_w[64 + lane]);
  if (lane == 0) { sAt[b] = sa; sBt[b] = sb; }
}

// ---------------- Adam per-param update ----------------
__device__ __forceinline__ void adam1(float& p, float& m, float& v, float g,
                                      float rc1, float rc2) {
  m = fmaf(B1C, m, C1C * g);
  v = fmaf(B2C, v, (C2C * g) * g);
  float den = sqrtf(v * rc2) + EPSC;
  p = fmaf(-LRC, __fdividef(m * rc1, den), p);
}

// ---------------- K2: table-scored evict-min -> 8 Adam steps -> query ----------------
// block = 256 (4 waves), one sample per wave; lane = feature index j.
__global__ __launch_bounds__(256, 2) void adam_kernel(
    const int* __restrict__ seqs, const float* __restrict__ enc,
    const float* __restrict__ sAt, const float* __restrict__ sBt,
    const float* __restrict__ scorer_b,
    const float* __restrict__ mlp_w1, const float* __restrict__ mlp_b1,
    const float* __restrict__ mlp_w2, const float* __restrict__ mlp_b2,
    const float* __restrict__ out_w, const float* __restrict__ out_b,
    float* __restrict__ out)
{
  const int wave = threadIdx.x >> 6;
  const int lane = threadIdx.x & 63;
  const int sample = blockIdx.x * 4 + wave;

  int tv = seqs[sample * 32 + (lane & 31)];
  float sbv = scorer_b[0];

  // scores from factored tables (wave-uniform)
  float sc[15]; int ta[15], tb[15];
  #pragma unroll
  for (int p = 0; p < 15; ++p) {
    ta[p] = __builtin_amdgcn_readlane(tv, 2 * p);
    tb[p] = __builtin_amdgcn_readlane(tv, 2 * p + 1);
    sc[p] = sAt[ta[p]] + sBt[tb[p]] + sbv;
  }
  int q30 = __builtin_amdgcn_readlane(tv, 30);

  // evict-min on (score, token-id) triples; strict < keeps FIRST min
  float bs[8]; int bka[8], bva[8];
  #pragma unroll
  for (int i = 0; i < 8; ++i) { bs[i] = sc[i]; bka[i] = ta[i]; bva[i] = tb[i]; }
  #pragma unroll
  for (int n = 0; n < 7; ++n) {
    int mi = 0; float ms = bs[0];
    #pragma unroll
    for (int i = 1; i < 8; ++i) {
      if (bs[i] < ms) { mi = i; ms = bs[i]; }
    }
    #pragma unroll
    for (int i = 0; i < 7; ++i) {
      bool sh = i >= mi;
      bs[i]  = sh ? bs[i + 1]  : bs[i];
      bka[i] = sh ? bka[i + 1] : bka[i];
      bva[i] = sh ? bva[i + 1] : bva[i];
    }
    bs[7] = sc[8 + n]; bka[7] = ta[8 + n]; bva[7] = tb[8 + n];
  }

  // tmp MLP params: lane j holds w1 row j, w2 col j; b1 lane-distributed
  float w1r[24], w2c[24], m1[24], v1[24], m2[24], v2[24];
  #pragma unroll
  for (int c = 0; c < 24; ++c) {
    w1r[c] = mlp_w1[lane * 24 + c];
    w2c[c] = mlp_w2[c * 64 + lane];
    m1[c] = v1[c] = m2[c] = v2[c] = 0.f;
  }
  float b1o = (lane < 24) ? mlp_b1[lane] : 0.f;
  float b2o = mlp_b2[lane];
  float mb1 = 0.f, vb1 = 0.f, mb2 = 0.f, vb2 = 0.f;
  float p1t = 1.f, p2t = 1.f;

  #pragma unroll 1
  for (int step = 0; step < 8; ++step) {
    int ka = bka[0], va = bva[0];
    #pragma unroll
    for (int i = 1; i < 8; ++i)
      if (step == i) { ka = bka[i]; va = bva[i]; }
    float kj = enc[ka * 64 + lane];   // L1-resident 16 KB table
    float vj = enc[va * 64 + lane];

    p1t *= B1C; p2t *= B2C;
    float rc1 = __fdividef(1.f, 1.f - p1t);
    float rc2 = __fdividef(1.f, 1.f - p2t);

    // fwd layer1: a[c] = relu(b1[c] + sum_j k_j*w1[j][c]), replicated
    float a[24];
    #pragma unroll
    for (int c = 0; c < 24; ++c) a[c] = kj * w1r[c];
    wave_sum_batch<24>(a);
    #pragma unroll
    for (int c = 0; c < 24; ++c) a[c] = fmaxf(a[c] + rlane(b1o, c), 0.f);

    // fwd layer2 (lane-local)
    float outv = b2o;
    #pragma unroll
    for (int c = 0; c < 24; ++c) outv = fmaf(a[c], w2c[c], outv);
    float dout = (outv - vj) * (2.f / 64.f);

    // dh[c] = sum_j w2[c][j]*dout_j, replicated
    float dh[24];
    #pragma unroll
    for (int c = 0; c < 24; ++c) dh[c] = w2c[c] * dout;
    wave_sum_batch<24>(dh);

    // dpre = dh * relu'(pre); a>0 <=> pre>0
    float dpre_own = 0.f;
    #pragma unroll
    for (int c = 0; c < 24; ++c) {
      float dp = (a[c] > 0.f) ? dh[c] : 0.f;
      dh[c] = dp;
      if (lane == c) dpre_own = dp;
    }

    #pragma unroll
    for (int c = 0; c < 24; ++c) {
      adam1(w1r[c], m1[c], v1[c], kj * dh[c], rc1, rc2);   // gw1[j][c]
      adam1(w2c[c], m2[c], v2[c], a[c] * dout, rc1, rc2);  // gw2[c][j]
    }
    adam1(b1o, mb1, vb1, dpre_own, rc1, rc2);
    adam1(b2o, mb2, vb2, dout, rc1, rc2);
  }

  // query: enc[tok30] through finetuned MLP, then output head
  float qj = enc[q30 * 64 + lane];
  float a[24];
  #pragma unroll
  for (int c = 0; c < 24; ++c) a[c] = qj * w1r[c];
  wave_sum_batch<24>(a);
  #pragma unroll
  for (int c = 0; c < 24; ++c) a[c] = fmaxf(a[c] + rlane(b1o, c), 0.f);
  float y = b2o;
  #pragma unroll
  for (int c = 0; c < 24; ++c) y = fmaf(a[c], w2c[c], y);

  float acc = out_b[lane];
  #pragma unroll
  for (int l = 0; l < 64; ++l)
    acc = fmaf(rlane(y, l), out_w[l * 64 + lane], acc);

  out[(size_t)sample * 64 + lane] = acc;
}

extern "C" void kernel_launch(void* const* d_in, const int* in_sizes, int n_in,
                              void* d_out, int out_size, void* d_ws, size_t ws_size,
                              hipStream_t stream) {
  const int*   seqs     = (const int*)d_in[0];
  const float* embed    = (const float*)d_in[1];
  const float* ff_w1    = (const float*)d_in[2];
  const float* ff_b1    = (const float*)d_in[3];
  const float* ff_w2    = (const float*)d_in[4];
  const float* ff_b2    = (const float*)d_in[5];
  const float* ln_g     = (const float*)d_in[6];
  const float* ln_b     = (const float*)d_in[7];
  const float* scorer_w = (const float*)d_in[8];
  const float* scorer_b = (const float*)d_in[9];
  const float* mlp_w1   = (const float*)d_in[10];
  const float* mlp_b1   = (const float*)d_in[11];
  const float* mlp_w2   = (const float*)d_in[12];
  const float* mlp_b2   = (const float*)d_in[13];
  const float* out_w    = (const float*)d_in[14];
  const float* out_b    = (const float*)d_in[15];

  const int B = in_sizes[0] / 32;        // 16384
  float* enc = (float*)d_ws;             // 64*64 floats = 16 KB
  float* sAt = enc + 64 * 64;            // 64 floats
  float* sBt = sAt + 64;                 // 64 floats

  enc_kernel<<<64, 64, 0, stream>>>(embed, ff_w1, ff_b1, ff_w2, ff_b2,
                                    ln_g, ln_b, scorer_w, enc, sAt, sBt);
  adam_kernel<<<B / 4, 256, 0, stream>>>(seqs, enc, sAt, sBt, scorer_b,
                                         mlp_w1, mlp_b1, mlp_w2, mlp_b2,
                                         out_w, out_b, (float*)d_out);
}

// Round 4
// 682.810 us; speedup vs baseline: 3.7459x; 1.0054x over previous
//
#include <hip/hip_runtime.h>

#define LRC   0.05f
#define B1C   0.9f
#define B2C   0.999f
#define C1C   0.1f      // float(1 - 0.9)
#define C2C   0.001f    // float(1 - 0.999)
#define EPSC  1e-8f

__device__ __forceinline__ float rlane(float v, int l) {
  return __int_as_float(__builtin_amdgcn_readlane(__float_as_int(v), l));
}

// sum-reduce step within 16-lane row via DPP rotate (VALU pipe, no LDS traffic)
template <int CTRL>
__device__ __forceinline__ float dpp_add(float x) {
  int y = __builtin_amdgcn_update_dpp(0, __float_as_int(x), CTRL, 0xF, 0xF, false);
  return x + __int_as_float(y);
}

// full-wave sum, result replicated in all 64 lanes
__device__ __forceinline__ float wave_sum_repl(float x) {
  x = dpp_add<0x121>(x);            // row_ror:1
  x = dpp_add<0x122>(x);            // row_ror:2
  x = dpp_add<0x124>(x);            // row_ror:4
  x = dpp_add<0x128>(x);            // row_ror:8  -> row sums
  x += __shfl_xor(x, 16, 64);
  x += __shfl_xor(x, 32, 64);
  return x;
}

// batch of N replicated wave sums, stage-interleaved for ILP
template <int N>
__device__ __forceinline__ void wave_sum_batch(float* a) {
  #pragma unroll
  for (int c = 0; c < N; ++c) a[c] = dpp_add<0x121>(a[c]);
  #pragma unroll
  for (int c = 0; c < N; ++c) a[c] = dpp_add<0x122>(a[c]);
  #pragma unroll
  for (int c = 0; c < N; ++c) a[c] = dpp_add<0x124>(a[c]);
  #pragma unroll
  for (int c = 0; c < N; ++c) a[c] = dpp_add<0x128>(a[c]);
  #pragma unroll
  for (int c = 0; c < N; ++c) a[c] += __shfl_xor(a[c], 16, 64);
  #pragma unroll
  for (int c = 0; c < N; ++c) a[c] += __shfl_xor(a[c], 32, 64);
}

// bias-correction constants: 1/(1-b^t), t=1..8 (compile-time, fp64-rounded)
__constant__ float RC1T[8] = {10.0f, 5.2631578947f, 3.6900369004f, 2.9078220413f,
                              2.4419428585f, 2.1342007905f, 1.9167972515f, 1.7558143540f};
__constant__ float RC2T[8] = {1000.0f, 500.2501251f, 333.6669446f, 250.3753310f,
                              200.4003604f, 167.0837822f, 143.2862774f, 125.4381714f};

// ---------------- K1: encode table for the 64 distinct tokens ----------------
__global__ void enc_kernel(
    const float* __restrict__ embed,
    const float* __restrict__ ff_w1, const float* __restrict__ ff_b1,
    const float* __restrict__ ff_w2, const float* __restrict__ ff_b2,
    const float* __restrict__ ln_g, const float* __restrict__ ln_b,
    const float* __restrict__ scorer_w,
    float* __restrict__ enc, float* __restrict__ sAt, float* __restrict__ sBt)
{
  const int b = blockIdx.x;      // token id
  const int lane = threadIdx.x;  // feature

  float e = embed[b * 64 + lane];
  float acc0 = ff_b1[lane], acc1 = ff_b1[64 + lane];
  #pragma unroll
  for (int j = 0; j < 64; ++j) {
    float ej = rlane(e, j);
    acc0 = fmaf(ej, ff_w1[j * 128 + lane], acc0);
    acc1 = fmaf(ej, ff_w1[j * 128 + 64 + lane], acc1);
  }
  acc0 = fmaxf(acc0, 0.f);
  acc1 = fmaxf(acc1, 0.f);

  float f = ff_b2[lane];
  #pragma unroll
  for (int l = 0; l < 64; ++l) {
    f = fmaf(rlane(acc0, l), ff_w2[l * 64 + lane], f);
    f = fmaf(rlane(acc1, l), ff_w2[(l + 64) * 64 + lane], f);
  }

  float x = e + f;
  float mu = wave_sum_repl(x) * (1.f / 64.f);
  float d = x - mu;
  float var = wave_sum_repl(d * d) * (1.f / 64.f);
  float h = d * (1.f / sqrtf(var + 1e-5f)) * ln_g[lane] + ln_b[lane];
  enc[b * 64 + lane] = h;

  float sa = wave_sum_repl(h * scorer_w[lane]);
  float sb = wave_sum_repl(h * scorer_w[64 + lane]);
  if (lane == 0) { sAt[b] = sa; sBt[b] = sb; }
}

// ---------------- Adam per-param update ----------------
// lrrc1 = LR/(1-b1^t) pre-folded; rc2 = 1/(1-b2^t)
__device__ __forceinline__ void adam1(float& p, float& m, float& v, float g,
                                      float lrrc1, float rc2) {
  m = fmaf(B1C, m, C1C * g);
  v = fmaf(B2C, v, (C2C * g) * g);
  float den = sqrtf(v * rc2) + EPSC;
  p = fmaf(-lrrc1, __fdividef(m, den), p);
}

// ---------------- K2: table-scored evict-min -> 8 Adam steps -> query ----------------
// block = 256 (4 waves), one sample per wave; lane = feature index j.
// launch_bounds(256,1): allow up to 512 VGPRs -> ~240 live regs, NO spills
// (at (256,2) the 128-VGPR cap spilled ~100 values through v_accvgpr moves).
__global__ __launch_bounds__(256, 1) void adam_kernel(
    const int* __restrict__ seqs, const float* __restrict__ enc,
    const float* __restrict__ sAt, const float* __restrict__ sBt,
    const float* __restrict__ scorer_b,
    const float* __restrict__ mlp_w1, const float* __restrict__ mlp_b1,
    const float* __restrict__ mlp_w2, const float* __restrict__ mlp_b2,
    const float* __restrict__ out_w, const float* __restrict__ out_b,
    float* __restrict__ out)
{
  const int wave = threadIdx.x >> 6;
  const int lane = threadIdx.x & 63;
  const int sample = blockIdx.x * 4 + wave;

  int tv = seqs[sample * 32 + (lane & 31)];
  float sbv = scorer_b[0];

  // scores from factored tables (all wave-uniform -> SALU/SGPR)
  float sc[15]; int ta[15], tb[15];
  #pragma unroll
  for (int p = 0; p < 15; ++p) {
    ta[p] = __builtin_amdgcn_readlane(tv, 2 * p);
    tb[p] = __builtin_amdgcn_readlane(tv, 2 * p + 1);
    sc[p] = sAt[ta[p]] + sBt[tb[p]] + sbv;
  }
  int q30 = __builtin_amdgcn_readlane(tv, 30);

  // evict-min on (score, token-id) triples; strict < keeps FIRST min
  float bs[8]; int bka[8], bva[8];
  #pragma unroll
  for (int i = 0; i < 8; ++i) { bs[i] = sc[i]; bka[i] = ta[i]; bva[i] = tb[i]; }
  #pragma unroll
  for (int n = 0; n < 7; ++n) {
    int mi = 0; float ms = bs[0];
    #pragma unroll
    for (int i = 1; i < 8; ++i) {
      if (bs[i] < ms) { mi = i; ms = bs[i]; }
    }
    #pragma unroll
    for (int i = 0; i < 7; ++i) {
      bool sh = i >= mi;
      bs[i]  = sh ? bs[i + 1]  : bs[i];
      bka[i] = sh ? bka[i + 1] : bka[i];
      bva[i] = sh ? bva[i + 1] : bva[i];
    }
    bs[7] = sc[8 + n]; bka[7] = ta[8 + n]; bva[7] = tb[8 + n];
  }

  // tmp MLP params: lane j holds w1 row j, w2 col j; b1 lane-distributed
  float w1r[24], w2c[24], m1[24], v1[24], m2[24], v2[24];
  #pragma unroll
  for (int c = 0; c < 24; ++c) {
    w1r[c] = mlp_w1[lane * 24 + c];
    w2c[c] = mlp_w2[c * 64 + lane];
    m1[c] = v1[c] = m2[c] = v2[c] = 0.f;
  }
  float b1o = (lane < 24) ? mlp_b1[lane] : 0.f;
  float b2o = mlp_b2[lane];
  float mb1 = 0.f, vb1 = 0.f, mb2 = 0.f, vb2 = 0.f;

  // software-pipelined (k,v) pair loads: prefetch step 0 now
  float kj = enc[bka[0] * 64 + lane];
  float vj = enc[bva[0] * 64 + lane];

  #pragma unroll 1
  for (int step = 0; step < 8; ++step) {
    // prefetch next step's pair (clamped; uniform select -> SALU)
    int nidx = (step < 7) ? step + 1 : 7;
    int kan = bka[0], van = bva[0];
    #pragma unroll
    for (int i = 1; i < 8; ++i)
      if (nidx == i) { kan = bka[i]; van = bva[i]; }
    float kjn = enc[kan * 64 + lane];
    float vjn = enc[van * 64 + lane];

    float lrrc1 = LRC * RC1T[step];
    float rc2 = RC2T[step];

    // fwd layer1: a[c] = relu(b1[c] + sum_j k_j*w1[j][c]), replicated
    float a[24];
    #pragma unroll
    for (int c = 0; c < 24; ++c) a[c] = kj * w1r[c];
    wave_sum_batch<24>(a);
    #pragma unroll
    for (int c = 0; c < 24; ++c) a[c] = fmaxf(a[c] + rlane(b1o, c), 0.f);

    // fwd layer2 (lane-local)
    float outv = b2o;
    #pragma unroll
    for (int c = 0; c < 24; ++c) outv = fmaf(a[c], w2c[c], outv);
    float dout = (outv - vj) * (2.f / 64.f);

    // dh[c] = sum_j w2[c][j]*dout_j, replicated
    float dh[24];
    #pragma unroll
    for (int c = 0; c < 24; ++c) dh[c] = w2c[c] * dout;
    wave_sum_batch<24>(dh);

    // dpre = dh * relu'(pre); a>0 <=> pre>0
    float dpre_own = 0.f;
    #pragma unroll
    for (int c = 0; c < 24; ++c) {
      float dp = (a[c] > 0.f) ? dh[c] : 0.f;
      dh[c] = dp;
      if (lane == c) dpre_own = dp;
    }

    #pragma unroll
    for (int c = 0; c < 24; ++c) {
      adam1(w1r[c], m1[c], v1[c], kj * dh[c], lrrc1, rc2);   // gw1[j][c]
      adam1(w2c[c], m2[c], v2[c], a[c] * dout, lrrc1, rc2);  // gw2[c][j]
    }
    adam1(b1o, mb1, vb1, dpre_own, lrrc1, rc2);
    adam1(b2o, mb2, vb2, dout, lrrc1, rc2);

    kj = kjn; vj = vjn;
  }

  // query: enc[tok30] through finetuned MLP, then output head
  float qj = enc[q30 * 64 + lane];
  float a[24];
  #pragma unroll
  for (int c = 0; c < 24; ++c) a[c] = qj * w1r[c];
  wave_sum_batch<24>(a);
  #pragma unroll
  for (int c = 0; c < 24; ++c) a[c] = fmaxf(a[c] + rlane(b1o, c), 0.f);
  float y = b2o;
  #pragma unroll
  for (int c = 0; c < 24; ++c) y = fmaf(a[c], w2c[c], y);

  float acc = out_b[lane];
  #pragma unroll
  for (int l = 0; l < 64; ++l)
    acc = fmaf(rlane(y, l), out_w[l * 64 + lane], acc);

  out[(size_t)sample * 64 + lane] = acc;
}

extern "C" void kernel_launch(void* const* d_in, const int* in_sizes, int n_in,
                              void* d_out, int out_size, void* d_ws, size_t ws_size,
                              hipStream_t stream) {
  const int*   seqs     = (const int*)d_in[0];
  const float* embed    = (const float*)d_in[1];
  const float* ff_w1    = (const float*)d_in[2];
  const float* ff_b1    = (const float*)d_in[3];
  const float* ff_w2    = (const float*)d_in[4];
  const float* ff_b2    = (const float*)d_in[5];
  const float* ln_g     = (const float*)d_in[6];
  const float* ln_b     = (const float*)d_in[7];
  const float* scorer_w = (const float*)d_in[8];
  const float* scorer_b = (const float*)d_in[9];
  const float* mlp_w1   = (const float*)d_in[10];
  const float* mlp_b1   = (const float*)d_in[11];
  const float* mlp_w2   = (const float*)d_in[12];
  const float* mlp_b2   = (const float*)d_in[13];
  const float* out_w    = (const float*)d_in[14];
  const float* out_b    = (const float*)d_in[15];

  const int B = in_sizes[0] / 32;        // 16384
  float* enc = (float*)d_ws;             // 64*64 floats = 16 KB
  float* sAt = enc + 64 * 64;            // 64 floats
  float* sBt = sAt + 64;                 // 64 floats

  enc_kernel<<<64, 64, 0, stream>>>(embed, ff_w1, ff_b1, ff_w2, ff_b2,
                                    ln_g, ln_b, scorer_w, enc, sAt, sBt);
  adam_kernel<<<B / 4, 256, 0, stream>>>(seqs, enc, sAt, sBt, scorer_b,
                                         mlp_w1, mlp_b1, mlp_w2, mlp_b2,
                                         out_w, out_b, (float*)d_out);
}

// Round 5
// 647.526 us; speedup vs baseline: 3.9500x; 1.0545x over previous
//
#include <hip/hip_runtime.h>

#define LRC   0.05f
#define B1C   0.9f
#define B2C   0.999f
#define C1C   0.1f      // float(1 - 0.9)
#define C2C   0.001f    // float(1 - 0.999)
#define EPSC  1e-8f

__device__ __forceinline__ float rlane(float v, int l) {
  return __int_as_float(__builtin_amdgcn_readlane(__float_as_int(v), l));
}

// sum-reduce step within 16-lane row via DPP rotate (VALU pipe, no LDS traffic)
template <int CTRL>
__device__ __forceinline__ float dpp_add(float x) {
  int y = __builtin_amdgcn_update_dpp(0, __float_as_int(x), CTRL, 0xF, 0xF, false);
  return x + __int_as_float(y);
}

// full-wave sum, result replicated in all 64 lanes
__device__ __forceinline__ float wave_sum_repl(float x) {
  x = dpp_add<0x121>(x);            // row_ror:1
  x = dpp_add<0x122>(x);            // row_ror:2
  x = dpp_add<0x124>(x);            // row_ror:4
  x = dpp_add<0x128>(x);            // row_ror:8  -> row sums
  x += __shfl_xor(x, 16, 64);
  x += __shfl_xor(x, 32, 64);
  return x;
}

// batch of N replicated wave sums, stage-interleaved for ILP
template <int N>
__device__ __forceinline__ void wave_sum_batch(float* a) {
  #pragma unroll
  for (int c = 0; c < N; ++c) a[c] = dpp_add<0x121>(a[c]);
  #pragma unroll
  for (int c = 0; c < N; ++c) a[c] = dpp_add<0x122>(a[c]);
  #pragma unroll
  for (int c = 0; c < N; ++c) a[c] = dpp_add<0x124>(a[c]);
  #pragma unroll
  for (int c = 0; c < N; ++c) a[c] = dpp_add<0x128>(a[c]);
  #pragma unroll
  for (int c = 0; c < N; ++c) a[c] += __shfl_xor(a[c], 16, 64);
  #pragma unroll
  for (int c = 0; c < N; ++c) a[c] += __shfl_xor(a[c], 32, 64);
}

// bias-correction constants: 1/(1-b^t), t=1..8
__constant__ float RC1T[8] = {10.0f, 5.2631578947f, 3.6900369004f, 2.9078220413f,
                              2.4419428585f, 2.1342007905f, 1.9167972515f, 1.7558143540f};
__constant__ float RC2T[8] = {1000.0f, 500.2501251f, 333.6669446f, 250.3753310f,
                              200.4003604f, 167.0837822f, 143.2862774f, 125.4381714f};

// ---------------- K1: encode table for the 64 distinct tokens ----------------
__global__ void enc_kernel(
    const float* __restrict__ embed,
    const float* __restrict__ ff_w1, const float* __restrict__ ff_b1,
    const float* __restrict__ ff_w2, const float* __restrict__ ff_b2,
    const float* __restrict__ ln_g, const float* __restrict__ ln_b,
    const float* __restrict__ scorer_w,
    float* __restrict__ enc, float* __restrict__ sAt, float* __restrict__ sBt)
{
  const int b = blockIdx.x;      // token id
  const int lane = threadIdx.x;  // feature

  float e = embed[b * 64 + lane];
  float acc0 = ff_b1[lane], acc1 = ff_b1[64 + lane];
  #pragma unroll
  for (int j = 0; j < 64; ++j) {
    float ej = rlane(e, j);
    acc0 = fmaf(ej, ff_w1[j * 128 + lane], acc0);
    acc1 = fmaf(ej, ff_w1[j * 128 + 64 + lane], acc1);
  }
  acc0 = fmaxf(acc0, 0.f);
  acc1 = fmaxf(acc1, 0.f);

  float f = ff_b2[lane];
  #pragma unroll
  for (int l = 0; l < 64; ++l) {
    f = fmaf(rlane(acc0, l), ff_w2[l * 64 + lane], f);
    f = fmaf(rlane(acc1, l), ff_w2[(l + 64) * 64 + lane], f);
  }

  float x = e + f;
  float mu = wave_sum_repl(x) * (1.f / 64.f);
  float d = x - mu;
  float var = wave_sum_repl(d * d) * (1.f / 64.f);
  float h = d * (1.f / sqrtf(var + 1e-5f)) * ln_g[lane] + ln_b[lane];
  enc[b * 64 + lane] = h;

  float sa = wave_sum_repl(h * scorer_w[lane]);
  float sb = wave_sum_repl(h * scorer_w[64 + lane]);
  if (lane == 0) { sAt[b] = sa; sBt[b] = sb; }
}

// ---------------- Adam per-param update ----------------
__device__ __forceinline__ void adam1(float& p, float& m, float& v, float g,
                                      float lrrc1, float rc2) {
  m = fmaf(B1C, m, C1C * g);
  v = fmaf(B2C, v, (C2C * g) * g);
  float den = sqrtf(v * rc2) + EPSC;
  p = fmaf(-lrrc1, __fdividef(m, den), p);
}

// ---------------- K2: two waves per sample, hidden units split 12/12 ----------------
// block = 256 (4 waves) = 2 samples. wave = (sample-in-block, half).
// Per-lane param state: 72 floats (vs 144 single-wave) -> fits arch VGPRs,
// no AGPR residency, 3-4 waves/SIMD occupancy. One barrier per Adam step
// (parity double-buffered outv exchange through LDS).
__global__ __launch_bounds__(256, 3) void adam_kernel(
    const int* __restrict__ seqs, const float* __restrict__ enc,
    const float* __restrict__ sAt, const float* __restrict__ sBt,
    const float* __restrict__ scorer_b,
    const float* __restrict__ mlp_w1, const float* __restrict__ mlp_b1,
    const float* __restrict__ mlp_w2, const float* __restrict__ mlp_b2,
    const float* __restrict__ out_w, const float* __restrict__ out_b,
    float* __restrict__ out)
{
  const int wid  = threadIdx.x >> 6;
  const int lane = threadIdx.x & 63;
  const int sblk = wid >> 1;           // sample within block
  const int half = wid & 1;            // which 12 hidden units we own
  const int c0   = half * 12;
  const int sample = blockIdx.x * 2 + sblk;

  __shared__ float xbuf[2][2][2][64];  // [sblk][parity][half][lane]

  int tv = seqs[sample * 32 + (lane & 31)];
  float sbv = scorer_b[0];

  // scores from factored tables (wave-uniform; both halves compute identically)
  float sc[15]; int ta[15], tb[15];
  #pragma unroll
  for (int p = 0; p < 15; ++p) {
    ta[p] = __builtin_amdgcn_readlane(tv, 2 * p);
    tb[p] = __builtin_amdgcn_readlane(tv, 2 * p + 1);
    sc[p] = sAt[ta[p]] + sBt[tb[p]] + sbv;
  }
  int q30 = __builtin_amdgcn_readlane(tv, 30);

  // evict-min on (score, token-id); strict < keeps FIRST min
  float bs[8]; int bka[8], bva[8];
  #pragma unroll
  for (int i = 0; i < 8; ++i) { bs[i] = sc[i]; bka[i] = ta[i]; bva[i] = tb[i]; }
  #pragma unroll
  for (int n = 0; n < 7; ++n) {
    int mi = 0; float ms = bs[0];
    #pragma unroll
    for (int i = 1; i < 8; ++i) {
      if (bs[i] < ms) { mi = i; ms = bs[i]; }
    }
    #pragma unroll
    for (int i = 0; i < 7; ++i) {
      bool sh = i >= mi;
      bs[i]  = sh ? bs[i + 1]  : bs[i];
      bka[i] = sh ? bka[i + 1] : bka[i];
      bva[i] = sh ? bva[i + 1] : bva[i];
    }
    bs[7] = sc[8 + n]; bka[7] = ta[8 + n]; bva[7] = tb[8 + n];
  }

  // own params: lane j holds w1[j][c0+c], w2[c0+c][j]; b1 lane-distributed on own range
  float w1r[12], w2c[12], m1[12], v1[12], m2[12], v2[12];
  #pragma unroll
  for (int c = 0; c < 12; ++c) {
    w1r[c] = mlp_w1[lane * 24 + c0 + c];
    w2c[c] = mlp_w2[(c0 + c) * 64 + lane];
    m1[c] = v1[c] = m2[c] = v2[c] = 0.f;
  }
  float b1o = (lane >= c0 && lane < c0 + 12) ? mlp_b1[lane] : 0.f;
  float b2o = mlp_b2[lane];                      // replicated in both halves
  float mb1 = 0.f, vb1 = 0.f, mb2 = 0.f, vb2 = 0.f;

  float kj = enc[bka[0] * 64 + lane];
  float vj = enc[bva[0] * 64 + lane];

  #pragma unroll 1
  for (int step = 0; step < 8; ++step) {
    // prefetch next step's (k,v) pair
    int nidx = (step < 7) ? step + 1 : 7;
    int kan = bka[0], van = bva[0];
    #pragma unroll
    for (int i = 1; i < 8; ++i)
      if (nidx == i) { kan = bka[i]; van = bva[i]; }
    float kjn = enc[kan * 64 + lane];
    float vjn = enc[van * 64 + lane];

    float lrrc1 = LRC * RC1T[step];
    float rc2 = RC2T[step];

    // layer1 for own 12 units: a[c] = relu(b1[c0+c] + sum_j k_j w1[j][c0+c])
    float a[12];
    #pragma unroll
    for (int c = 0; c < 12; ++c) a[c] = kj * w1r[c];
    wave_sum_batch<12>(a);
    #pragma unroll
    for (int c = 0; c < 12; ++c) a[c] = fmaxf(a[c] + rlane(b1o, c0 + c), 0.f);

    // partial layer2 output (half 0 carries the bias)
    float po = half ? 0.f : b2o;
    #pragma unroll
    for (int c = 0; c < 12; ++c) po = fmaf(a[c], w2c[c], po);

    // exchange partials (parity double-buffer -> one barrier per step)
    xbuf[sblk][step & 1][half][lane] = po;
    __syncthreads();
    float qo = xbuf[sblk][step & 1][half ^ 1][lane];
    float outv = po + qo;                 // commutative -> bitwise equal in both halves
    float dout = (outv - vj) * (2.f / 64.f);

    // dh[c] = sum_j w2[c0+c][j] dout_j
    float dh[12];
    #pragma unroll
    for (int c = 0; c < 12; ++c) dh[c] = w2c[c] * dout;
    wave_sum_batch<12>(dh);

    float dpre_own = 0.f;
    #pragma unroll
    for (int c = 0; c < 12; ++c) {
      float dp = (a[c] > 0.f) ? dh[c] : 0.f;
      dh[c] = dp;
      if (lane == c0 + c) dpre_own = dp;
    }

    #pragma unroll
    for (int c = 0; c < 12; ++c) {
      adam1(w1r[c], m1[c], v1[c], kj * dh[c], lrrc1, rc2);   // gw1[j][c0+c]
      adam1(w2c[c], m2[c], v2[c], a[c] * dout, lrrc1, rc2);  // gw2[c0+c][j]
    }
    adam1(b1o, mb1, vb1, dpre_own, lrrc1, rc2);  // zero-grad no-op outside own range
    adam1(b2o, mb2, vb2, dout, lrrc1, rc2);      // identical trajectory in both halves

    kj = kjn; vj = vjn;
  }

  // ---- query: enc[tok30] through finetuned MLP ----
  float qj = enc[q30 * 64 + lane];
  float a[12];
  #pragma unroll
  for (int c = 0; c < 12; ++c) a[c] = qj * w1r[c];
  wave_sum_batch<12>(a);
  #pragma unroll
  for (int c = 0; c < 12; ++c) a[c] = fmaxf(a[c] + rlane(b1o, c0 + c), 0.f);
  float po = half ? 0.f : b2o;
  #pragma unroll
  for (int c = 0; c < 12; ++c) po = fmaf(a[c], w2c[c], po);

  xbuf[sblk][0][half][lane] = po;
  __syncthreads();
  float y = po + xbuf[sblk][0][half ^ 1][lane];   // full MLP output, bitwise equal

  // ---- output head, split over l: this half sums 32 of the 64 terms ----
  float acc = 0.f;
  #pragma unroll
  for (int i = 0; i < 32; ++i) {
    int l = half * 32 + i;
    acc = fmaf(rlane(y, l), out_w[l * 64 + lane], acc);
  }
  xbuf[sblk][1][half][lane] = acc;
  __syncthreads();
  if (half == 0) {
    float tot = acc + xbuf[sblk][1][1][lane] + out_b[lane];
    out[(size_t)sample * 64 + lane] = tot;
  }
}

extern "C" void kernel_launch(void* const* d_in, const int* in_sizes, int n_in,
                              void* d_out, int out_size, void* d_ws, size_t ws_size,
                              hipStream_t stream) {
  const int*   seqs     = (const int*)d_in[0];
  const float* embed    = (const float*)d_in[1];
  const float* ff_w1    = (const float*)d_in[2];
  const float* ff_b1    = (const float*)d_in[3];
  const float* ff_w2    = (const float*)d_in[4];
  const float* ff_b2    = (const float*)d_in[5];
  const float* ln_g     = (const float*)d_in[6];
  const float* ln_b     = (const float*)d_in[7];
  const float* scorer_w = (const float*)d_in[8];
  const float* scorer_b = (const float*)d_in[9];
  const float* mlp_w1   = (const float*)d_in[10];
  const float* mlp_b1   = (const float*)d_in[11];
  const float* mlp_w2   = (const float*)d_in[12];
  const float* mlp_b2   = (const float*)d_in[13];
  const float* out_w    = (const float*)d_in[14];
  const float* out_b    = (const float*)d_in[15];

  const int B = in_sizes[0] / 32;        // 16384
  float* enc = (float*)d_ws;             // 64*64 floats = 16 KB
  float* sAt = enc + 64 * 64;            // 64 floats
  float* sBt = sAt + 64;                 // 64 floats

  enc_kernel<<<64, 64, 0, stream>>>(embed, ff_w1, ff_b1, ff_w2, ff_b2,
                                    ln_g, ln_b, scorer_w, enc, sAt, sBt);
  adam_kernel<<<B / 2, 256, 0, stream>>>(seqs, enc, sAt, sBt, scorer_b,
                                         mlp_w1, mlp_b1, mlp_w2, mlp_b2,
                                         out_w, out_b, (float*)d_out);
}